// Round 1
// baseline (403.865 us; speedup 1.0000x reference)
//
#include <hip/hip_runtime.h>
#include <math.h>

#define IN_CH 128
#define G4    512   // 4*IN
#define K1    256   // 2*IN

__device__ __forceinline__ float sigmoidf_(float v){ return 1.f/(1.f + expf(-v)); }

// Transpose w_ih [512,256] -> wTih [256,512]; w_hh [512,128] -> wThh [128,512]
__global__ void transpose_w_kernel(const float* __restrict__ w_ih, const float* __restrict__ w_hh,
                                   float* __restrict__ wTih, float* __restrict__ wThh){
  int idx = blockIdx.x*blockDim.x + threadIdx.x;
  if (idx < G4*K1){ int g = idx / K1; int k = idx - g*K1; wTih[k*G4 + g] = w_ih[idx]; }
  if (idx < G4*IN_CH){ int g = idx / IN_CH; int k = idx - g*IN_CH; wThh[k*G4 + g] = w_hh[idx]; }
}

// segs[b] = lower_bound(batch, b); segs[B] = N   (batch is sorted)
__global__ void seg_bounds_kernel(const int* __restrict__ batch, int N, int B, int* __restrict__ segs){
  int b = blockIdx.x*blockDim.x + threadIdx.x;
  if (b > B) return;
  if (b == B){ segs[B] = N; return; }
  int lo = 0, hi = N;
  while (lo < hi){ int mid = (lo + hi) >> 1; if (batch[mid] < b) lo = mid + 1; else hi = mid; }
  segs[b] = lo;
}

// gates[b,g] = qstar[b,:] . wTih[:,g] + h[b,:] . wThh[:,g] + b_ih[g] + b_hh[g]
// 8 rows per block, thread-per-gate (2 gate-halves via blockIdx.y)
__global__ __launch_bounds__(256) void lstm_gemv_kernel(
    const float* __restrict__ qstar, const float* __restrict__ h,
    const float* __restrict__ wTih, const float* __restrict__ wThh,
    const float* __restrict__ b_ih, const float* __restrict__ b_hh,
    float* __restrict__ gates){
  int g    = blockIdx.y*256 + threadIdx.x;
  int row0 = blockIdx.x*8;
  __shared__ float qs[8][K1];
  __shared__ float hs[8][IN_CH];
  for (int t = threadIdx.x; t < 8*K1; t += 256){ int r = t >> 8; int k = t & 255; qs[r][k] = qstar[(row0+r)*K1 + k]; }
  for (int t = threadIdx.x; t < 8*IN_CH; t += 256){ int r = t >> 7; int k = t & 127; hs[r][k] = h[(row0+r)*IN_CH + k]; }
  __syncthreads();
  float bias = b_ih[g] + b_hh[g];
  float acc[8];
#pragma unroll
  for (int r = 0; r < 8; ++r) acc[r] = bias;
  for (int k4 = 0; k4 < K1/4; ++k4){
    float w0 = wTih[(4*k4+0)*G4 + g];
    float w1 = wTih[(4*k4+1)*G4 + g];
    float w2 = wTih[(4*k4+2)*G4 + g];
    float w3 = wTih[(4*k4+3)*G4 + g];
#pragma unroll
    for (int r = 0; r < 8; ++r){
      float4 q = *reinterpret_cast<const float4*>(&qs[r][4*k4]);
      acc[r] += q.x*w0 + q.y*w1 + q.z*w2 + q.w*w3;
    }
  }
  for (int k4 = 0; k4 < IN_CH/4; ++k4){
    float w0 = wThh[(4*k4+0)*G4 + g];
    float w1 = wThh[(4*k4+1)*G4 + g];
    float w2 = wThh[(4*k4+2)*G4 + g];
    float w3 = wThh[(4*k4+3)*G4 + g];
#pragma unroll
    for (int r = 0; r < 8; ++r){
      float4 hv = *reinterpret_cast<const float4*>(&hs[r][4*k4]);
      acc[r] += hv.x*w0 + hv.y*w1 + hv.z*w2 + hv.w*w3;
    }
  }
#pragma unroll
  for (int r = 0; r < 8; ++r) gates[(row0+r)*G4 + g] = acc[r];
}

// LSTM cell update; also writes q-half of q_star
__global__ void lstm_update_kernel(const float* __restrict__ gates,
                                   float* __restrict__ h, float* __restrict__ c,
                                   float* __restrict__ qstar, int B){
  int idx = blockIdx.x*blockDim.x + threadIdx.x;
  if (idx >= B*IN_CH) return;
  int b = idx >> 7, ch = idx & 127;
  const float* gr = gates + b*G4;
  float iv = sigmoidf_(gr[ch]);
  float fv = sigmoidf_(gr[IN_CH + ch]);
  float gv = tanhf(gr[2*IN_CH + ch]);
  float ov = sigmoidf_(gr[3*IN_CH + ch]);
  float cv = fv*c[idx] + iv*gv;
  float hv = ov*tanhf(cv);
  c[idx] = cv; h[idx] = hv;
  qstar[b*K1 + ch] = hv;
}

// One block per segment: softmax-weighted readout.
// Pass 1: e_j = x_j . q_b, track segment max. Pass 2: recompute e_j (x re-read is
// L2-hot), accumulate sum(exp * x) and sum(exp); write r to q_star[b, 128:256].
__global__ __launch_bounds__(256) void attn_kernel(const float* __restrict__ x,
                                                   float* __restrict__ qstar,
                                                   const int* __restrict__ segs){
  int b = blockIdx.x;
  int s = segs[b], t = segs[b+1];
  int tid = threadIdx.x;
  int wave = tid >> 6, lane = tid & 63;
  int half = lane >> 5, lane31 = lane & 31;
  const float4* x4 = reinterpret_cast<const float4*>(x);
  float4 qv = *reinterpret_cast<const float4*>(&qstar[b*K1 + lane31*4]);

  __shared__ float smax[4];
  __shared__ float rbuf[4][IN_CH];
  __shared__ float dbuf[4];

  // Pass 1: segment max of scores. 2 rows per wave per iteration (half-wave each).
  float wmax = -INFINITY;
  for (int j0 = s + wave*2; j0 < t; j0 += 8){
    int j = j0 + half;
    float part = 0.f;
    if (j < t){
      float4 xv = x4[j*(IN_CH/4) + lane31];
      part = xv.x*qv.x + xv.y*qv.y + xv.z*qv.z + xv.w*qv.w;
    }
    float dsum = part;
#pragma unroll
    for (int off = 1; off <= 16; off <<= 1) dsum += __shfl_xor(dsum, off);
    if (j < t) wmax = fmaxf(wmax, dsum);
  }
  wmax = fmaxf(wmax, __shfl_xor(wmax, 32));
  if (lane == 0) smax[wave] = wmax;
  __syncthreads();
  float m = fmaxf(fmaxf(smax[0], smax[1]), fmaxf(smax[2], smax[3]));

  // Pass 2: exp + weighted accumulate
  float4 racc = make_float4(0.f, 0.f, 0.f, 0.f);
  float dacc = 0.f;
  for (int j0 = s + wave*2; j0 < t; j0 += 8){
    int j = j0 + half;
    float4 xv = make_float4(0.f, 0.f, 0.f, 0.f);
    float part = 0.f;
    if (j < t){
      xv = x4[j*(IN_CH/4) + lane31];
      part = xv.x*qv.x + xv.y*qv.y + xv.z*qv.z + xv.w*qv.w;
    }
    float dsum = part;
#pragma unroll
    for (int off = 1; off <= 16; off <<= 1) dsum += __shfl_xor(dsum, off);
    float ex = (j < t) ? expf(dsum - m) : 0.f;
    racc.x += ex*xv.x; racc.y += ex*xv.y; racc.z += ex*xv.z; racc.w += ex*xv.w;
    if (lane31 == 0) dacc += ex;
  }
  racc.x += __shfl_xor(racc.x, 32);
  racc.y += __shfl_xor(racc.y, 32);
  racc.z += __shfl_xor(racc.z, 32);
  racc.w += __shfl_xor(racc.w, 32);
  dacc   += __shfl_xor(dacc, 32);
  if (lane < 32){
    rbuf[wave][lane31*4+0] = racc.x;
    rbuf[wave][lane31*4+1] = racc.y;
    rbuf[wave][lane31*4+2] = racc.z;
    rbuf[wave][lane31*4+3] = racc.w;
  }
  if (lane == 0) dbuf[wave] = dacc;
  __syncthreads();
  if (tid < IN_CH){
    float r   = rbuf[0][tid] + rbuf[1][tid] + rbuf[2][tid] + rbuf[3][tid];
    float den = dbuf[0] + dbuf[1] + dbuf[2] + dbuf[3];
    qstar[b*K1 + IN_CH + tid] = (den > 0.f) ? r/den : 0.f;
  }
}

extern "C" void kernel_launch(void* const* d_in, const int* in_sizes, int n_in,
                              void* d_out, int out_size, void* d_ws, size_t ws_size,
                              hipStream_t stream){
  const float* x     = (const float*)d_in[0];
  const float* w_ih  = (const float*)d_in[1];
  const float* w_hh  = (const float*)d_in[2];
  const float* b_ih  = (const float*)d_in[3];
  const float* b_hh  = (const float*)d_in[4];
  const int*   batch = (const int*)d_in[5];
  int N = in_sizes[0] / IN_CH;
  int B = out_size / K1;
  float* out = (float*)d_out;   // q_star lives here

  float* ws    = (float*)d_ws;
  float* h     = ws;                    // B*128
  float* c     = h + (size_t)B*IN_CH;   // B*128
  float* wTih  = c + (size_t)B*IN_CH;   // 256*512
  float* wThh  = wTih + K1*G4;          // 128*512
  float* gates = wThh + IN_CH*G4;       // B*512
  int*   segs  = (int*)(gates + (size_t)B*G4); // B+1

  hipMemsetAsync(h, 0, (size_t)B*IN_CH*2*sizeof(float), stream);
  hipMemsetAsync(d_out, 0, (size_t)out_size*sizeof(float), stream);
  transpose_w_kernel<<<(G4*K1 + 255)/256, 256, 0, stream>>>(w_ih, w_hh, wTih, wThh);
  seg_bounds_kernel<<<(B + 256)/256, 256, 0, stream>>>(batch, N, B, segs);

  for (int step = 0; step < 3; ++step){
    lstm_gemv_kernel<<<dim3(B/8, 2), 256, 0, stream>>>(out, h, wTih, wThh, b_ih, b_hh, gates);
    lstm_update_kernel<<<(B*IN_CH + 255)/256, 256, 0, stream>>>(gates, h, c, out, B);
    attn_kernel<<<B, 256, 0, stream>>>(x, out, segs);
  }
}

// Round 2
// 286.353 us; speedup vs baseline: 1.4104x; 1.4104x over previous
//
#include <hip/hip_runtime.h>
#include <math.h>

#define IN_CH 128
#define G4    512   // 4*IN
#define K1    256   // 2*IN
#define SPLIT 4     // blocks per segment in attention

__device__ __forceinline__ float sigmoidf_(float v){ return 1.f/(1.f + expf(-v)); }

// Transpose w_ih [512,256] -> wTih [256,512]; w_hh [512,128] -> wThh [128,512]
__global__ void transpose_w_kernel(const float* __restrict__ w_ih, const float* __restrict__ w_hh,
                                   float* __restrict__ wTih, float* __restrict__ wThh){
  int idx = blockIdx.x*blockDim.x + threadIdx.x;
  if (idx < G4*K1){ int g = idx / K1; int k = idx - g*K1; wTih[k*G4 + g] = w_ih[idx]; }
  if (idx < G4*IN_CH){ int g = idx / IN_CH; int k = idx - g*IN_CH; wThh[k*G4 + g] = w_hh[idx]; }
}

// segs[b] = lower_bound(batch, b); segs[B] = N   (batch is sorted)
__global__ void seg_bounds_kernel(const int* __restrict__ batch, int N, int B, int* __restrict__ segs){
  int b = blockIdx.x*blockDim.x + threadIdx.x;
  if (b > B) return;
  if (b == B){ segs[B] = N; return; }
  int lo = 0, hi = N;
  while (lo < hi){ int mid = (lo + hi) >> 1; if (batch[mid] < b) lo = mid + 1; else hi = mid; }
  segs[b] = lo;
}

// gates[b,g] = qstar[b,:] . wTih[:,g] + h[b,:] . wThh[:,g] + b_ih[g] + b_hh[g]
__global__ __launch_bounds__(256) void lstm_gemv_kernel(
    const float* __restrict__ qstar, const float* __restrict__ h,
    const float* __restrict__ wTih, const float* __restrict__ wThh,
    const float* __restrict__ b_ih, const float* __restrict__ b_hh,
    float* __restrict__ gates){
  int g    = blockIdx.y*256 + threadIdx.x;
  int row0 = blockIdx.x*8;
  __shared__ float qs[8][K1];
  __shared__ float hs[8][IN_CH];
  for (int t = threadIdx.x; t < 8*K1; t += 256){ int r = t >> 8; int k = t & 255; qs[r][k] = qstar[(row0+r)*K1 + k]; }
  for (int t = threadIdx.x; t < 8*IN_CH; t += 256){ int r = t >> 7; int k = t & 127; hs[r][k] = h[(row0+r)*IN_CH + k]; }
  __syncthreads();
  float bias = b_ih[g] + b_hh[g];
  float acc[8];
#pragma unroll
  for (int r = 0; r < 8; ++r) acc[r] = bias;
  for (int k4 = 0; k4 < K1/4; ++k4){
    float w0 = wTih[(4*k4+0)*G4 + g];
    float w1 = wTih[(4*k4+1)*G4 + g];
    float w2 = wTih[(4*k4+2)*G4 + g];
    float w3 = wTih[(4*k4+3)*G4 + g];
#pragma unroll
    for (int r = 0; r < 8; ++r){
      float4 q = *reinterpret_cast<const float4*>(&qs[r][4*k4]);
      acc[r] += q.x*w0 + q.y*w1 + q.z*w2 + q.w*w3;
    }
  }
  for (int k4 = 0; k4 < IN_CH/4; ++k4){
    float w0 = wThh[(4*k4+0)*G4 + g];
    float w1 = wThh[(4*k4+1)*G4 + g];
    float w2 = wThh[(4*k4+2)*G4 + g];
    float w3 = wThh[(4*k4+3)*G4 + g];
#pragma unroll
    for (int r = 0; r < 8; ++r){
      float4 hv = *reinterpret_cast<const float4*>(&hs[r][4*k4]);
      acc[r] += hv.x*w0 + hv.y*w1 + hv.z*w2 + hv.w*w3;
    }
  }
#pragma unroll
  for (int r = 0; r < 8; ++r) gates[(row0+r)*G4 + g] = acc[r];
}

// LSTM cell update; also writes q-half of q_star
__global__ void lstm_update_kernel(const float* __restrict__ gates,
                                   float* __restrict__ h, float* __restrict__ c,
                                   float* __restrict__ qstar, int B){
  int idx = blockIdx.x*blockDim.x + threadIdx.x;
  if (idx >= B*IN_CH) return;
  int b = idx >> 7, ch = idx & 127;
  const float* gr = gates + b*G4;
  float iv = sigmoidf_(gr[ch]);
  float fv = sigmoidf_(gr[IN_CH + ch]);
  float gv = tanhf(gr[2*IN_CH + ch]);
  float ov = sigmoidf_(gr[3*IN_CH + ch]);
  float cv = fv*c[idx] + iv*gv;
  float hv = ov*tanhf(cv);
  c[idx] = cv; h[idx] = hv;
  qstar[b*K1 + ch] = hv;
}

// Single-pass online-softmax weighted readout, SPLIT blocks per segment.
// Each block writes partial (m, d, r[128]) for its chunk.
__global__ __launch_bounds__(256) void attn_part_kernel(const float* __restrict__ x,
    const float* __restrict__ qstar, const int* __restrict__ segs,
    float* __restrict__ pm, float* __restrict__ pd, float* __restrict__ pr){
  int b = blockIdx.x, p = blockIdx.y;
  int s = segs[b], t = segs[b+1];
  int len = t - s;
  int cs = s + (len * p) / SPLIT;
  int ce = s + (len * (p+1)) / SPLIT;
  int tid = threadIdx.x;
  int wave = tid >> 6, lane = tid & 63;
  int half = lane >> 5, lane31 = lane & 31;
  const float4* x4 = reinterpret_cast<const float4*>(x);
  float4 qv = *reinterpret_cast<const float4*>(&qstar[b*K1 + lane31*4]);

  float m = -INFINITY, d = 0.f;
  float rx = 0.f, ry = 0.f, rz = 0.f, rw = 0.f;
  // half-wave (32 lanes) per row; 8 rows per block-iter, unroll 2 -> stride 16
  for (int j = cs + wave*2 + half; j < ce; j += 16){
    int j2 = j + 8;
    bool has2 = (j2 < ce);
    float4 xv = x4[(size_t)j*(IN_CH/4) + lane31];
    float4 xw = make_float4(0.f,0.f,0.f,0.f);
    if (has2) xw = x4[(size_t)j2*(IN_CH/4) + lane31];
    float e1 = xv.x*qv.x + xv.y*qv.y + xv.z*qv.z + xv.w*qv.w;
    float e2 = xw.x*qv.x + xw.y*qv.y + xw.z*qv.z + xw.w*qv.w;
#pragma unroll
    for (int off = 1; off <= 16; off <<= 1){
      e1 += __shfl_xor(e1, off);
      e2 += __shfl_xor(e2, off);
    }
    float mn = fmaxf(m, e1);
    float corr = expf(m - mn);     // m=-inf first iter -> corr=0, state zeroed
    float p1 = expf(e1 - mn);
    d = d*corr + p1;
    rx = rx*corr + p1*xv.x; ry = ry*corr + p1*xv.y; rz = rz*corr + p1*xv.z; rw = rw*corr + p1*xv.w;
    m = mn;
    if (has2){
      mn = fmaxf(m, e2);
      corr = expf(m - mn);
      float p2 = expf(e2 - mn);
      d = d*corr + p2;
      rx = rx*corr + p2*xw.x; ry = ry*corr + p2*xw.y; rz = rz*corr + p2*xw.z; rw = rw*corr + p2*xw.w;
      m = mn;
    }
  }
  // merge the two halves of each wave (same channels, xor 32)
  {
    float mo = __shfl_xor(m, 32);
    float dd = __shfl_xor(d, 32);
    float ox = __shfl_xor(rx, 32), oy = __shfl_xor(ry, 32);
    float oz = __shfl_xor(rz, 32), ow = __shfl_xor(rw, 32);
    float mn = fmaxf(m, mo);
    float c1 = (mn == -INFINITY) ? 0.f : expf(m - mn);
    float c2 = (mn == -INFINITY) ? 0.f : expf(mo - mn);
    d = d*c1 + dd*c2;
    rx = rx*c1 + ox*c2; ry = ry*c1 + oy*c2; rz = rz*c1 + oz*c2; rw = rw*c1 + ow*c2;
    m = mn;
  }
  __shared__ float mbuf[4], dbuf[4];
  __shared__ float rbuf[4][IN_CH];
  if (lane < 32){
    rbuf[wave][lane31*4+0] = rx; rbuf[wave][lane31*4+1] = ry;
    rbuf[wave][lane31*4+2] = rz; rbuf[wave][lane31*4+3] = rw;
  }
  if (lane == 0){ mbuf[wave] = m; dbuf[wave] = d; }
  __syncthreads();
  int part = b*SPLIT + p;
  if (tid < IN_CH){
    float M = fmaxf(fmaxf(mbuf[0], mbuf[1]), fmaxf(mbuf[2], mbuf[3]));
    float f0 = (M == -INFINITY) ? 0.f : expf(mbuf[0] - M);
    float f1 = (M == -INFINITY) ? 0.f : expf(mbuf[1] - M);
    float f2 = (M == -INFINITY) ? 0.f : expf(mbuf[2] - M);
    float f3 = (M == -INFINITY) ? 0.f : expf(mbuf[3] - M);
    float R = rbuf[0][tid]*f0 + rbuf[1][tid]*f1 + rbuf[2][tid]*f2 + rbuf[3][tid]*f3;
    pr[(size_t)part*IN_CH + tid] = R;
    if (tid == 0){
      pd[part] = dbuf[0]*f0 + dbuf[1]*f1 + dbuf[2]*f2 + dbuf[3]*f3;
      pm[part] = M;
    }
  }
}

// Merge SPLIT partials per segment; write r-half of q_star
__global__ void attn_combine_kernel(const float* __restrict__ pm, const float* __restrict__ pd,
                                    const float* __restrict__ pr, float* __restrict__ qstar){
  int b = blockIdx.x; int ch = threadIdx.x;  // 128 threads
  float M = -INFINITY;
#pragma unroll
  for (int p = 0; p < SPLIT; ++p) M = fmaxf(M, pm[b*SPLIT + p]);
  float d = 0.f, r = 0.f;
#pragma unroll
  for (int p = 0; p < SPLIT; ++p){
    float mp = pm[b*SPLIT + p];
    float f = (mp == -INFINITY) ? 0.f : expf(mp - M);
    d += pd[b*SPLIT + p] * f;
    r += pr[(size_t)(b*SPLIT + p)*IN_CH + ch] * f;
  }
  qstar[b*K1 + IN_CH + ch] = (d > 0.f) ? r/d : 0.f;
}

extern "C" void kernel_launch(void* const* d_in, const int* in_sizes, int n_in,
                              void* d_out, int out_size, void* d_ws, size_t ws_size,
                              hipStream_t stream){
  const float* x     = (const float*)d_in[0];
  const float* w_ih  = (const float*)d_in[1];
  const float* w_hh  = (const float*)d_in[2];
  const float* b_ih  = (const float*)d_in[3];
  const float* b_hh  = (const float*)d_in[4];
  const int*   batch = (const int*)d_in[5];
  int N = in_sizes[0] / IN_CH;
  int B = out_size / K1;
  float* out = (float*)d_out;   // q_star lives here

  float* ws    = (float*)d_ws;
  float* h     = ws;                    // B*128
  float* c     = h + (size_t)B*IN_CH;   // B*128
  float* wTih  = c + (size_t)B*IN_CH;   // 256*512
  float* wThh  = wTih + K1*G4;          // 128*512
  float* gates = wThh + IN_CH*G4;       // B*512
  int*   segs  = (int*)(gates + (size_t)B*G4); // B+1
  float* pm    = (float*)(segs + (B + 2));     // B*SPLIT
  float* pd    = pm + (size_t)B*SPLIT;         // B*SPLIT
  float* pr    = pd + (size_t)B*SPLIT;         // B*SPLIT*128

  hipMemsetAsync(h, 0, (size_t)B*IN_CH*2*sizeof(float), stream);
  hipMemsetAsync(d_out, 0, (size_t)out_size*sizeof(float), stream);
  transpose_w_kernel<<<(G4*K1 + 255)/256, 256, 0, stream>>>(w_ih, w_hh, wTih, wThh);
  seg_bounds_kernel<<<(B + 256)/256, 256, 0, stream>>>(batch, N, B, segs);

  for (int step = 0; step < 3; ++step){
    lstm_gemv_kernel<<<dim3(B/8, 2), 256, 0, stream>>>(out, h, wTih, wThh, b_ih, b_hh, gates);
    lstm_update_kernel<<<(B*IN_CH + 255)/256, 256, 0, stream>>>(gates, h, c, out, B);
    attn_part_kernel<<<dim3(B, SPLIT), 256, 0, stream>>>(x, out, segs, pm, pd, pr);
    attn_combine_kernel<<<B, IN_CH, 0, stream>>>(pm, pd, pr, out);
  }
}